// Round 6
// baseline (491.174 us; speedup 1.0000x reference)
//
#include <hip/hip_runtime.h>
#include <math.h>

typedef float f32x4 __attribute__((ext_vector_type(4)));
typedef __attribute__((address_space(3))) unsigned int lds_u32;
typedef __attribute__((address_space(1))) const unsigned int glb_u32;

// ---------------------------------------------------------------------------
// R26: fused kernel with HAND-ROLLED grid barrier (R25's cooperative launch
// was silently rejected under graph capture: absmax == reference value ==
// kernel never ran). Co-residency is guaranteed by capacity arithmetic:
// LDS 34.3KB -> 4 blocks/CU hard cap, grid = 1024 = 256 CU x 4, 16 waves/CU
// <= 32, VGPR ~60. Barrier: release-fence all threads (buffer_wbl2 pushes
// Y8/P/Q to coherence point) -> counter atomicAdd by t0, last block sets
// flag, spin with agent-scope acquire loads (bounded: wrong-answer beats a
// killed container) -> acquire-fence all threads (buffer_inv so consumer
// XCDs can't serve stale poison lines to global_load_lds).
//
// Epilogue: normalization folds sqrt(log2e/T) so MFMA emits s*log2e and the
// epilogue is raw exp2f (saves 1 VALU mul/elem = ~12% of epilogue VALU);
// sacc rescaled by ln2 once per block. fp8 relative quant error is
// scale-invariant -> numerics unchanged.
// ---------------------------------------------------------------------------

__device__ __forceinline__ void grid_bar(int* cnt, int* flag, int nb) {
  __threadfence();  // release: every thread's prior writes -> coherence point
  __syncthreads();
  if (threadIdx.x == 0) {
    if (atomicAdd(cnt, 1) == nb - 1) {
      __hip_atomic_store(flag, 1, __ATOMIC_RELEASE, __HIP_MEMORY_SCOPE_AGENT);
    } else {
      int iter = 0;
      while (__hip_atomic_load(flag, __ATOMIC_ACQUIRE,
                               __HIP_MEMORY_SCOPE_AGENT) == 0) {
        __builtin_amdgcn_s_sleep(8);
        if (++iter > (1 << 22)) break;  // ~1s escape hatch: no hangs
      }
    }
  }
  __syncthreads();
  __threadfence();  // acquire: invalidate L1/L2 before reading others' data
}

// init: zero barrier state + out[0] (workspace is re-poisoned per iteration)
__global__ void init_kernel(int* __restrict__ bar, float* __restrict__ out) {
  if (threadIdx.x < 4) bar[threadIdx.x] = 0;
  if (threadIdx.x == 0) out[0] = 0.f;
}

__global__ __launch_bounds__(256, 4) void fused_kernel(
    const float* __restrict__ X, const int* __restrict__ lab,
    unsigned char* __restrict__ Y8, float* __restrict__ P,
    float* __restrict__ Q, float* __restrict__ S, int* __restrict__ bar,
    float* __restrict__ out, float scaleAB, int N) {
  __shared__ unsigned char As[128][128];    // chunk cc at (cc ^ (row&7))*16
  __shared__ unsigned char Bs[2][64][128];  // double-buffered 64-col halves
  __shared__ int labR[128];
  __shared__ float sS[4];
  __shared__ int hist[256];
  __shared__ float red[4];

  const int b = blockIdx.x;
  const int t = threadIdx.x;
  const int w = t >> 6, lane = t & 63;
  const int nb = gridDim.x;

  // ==== phase 0: normalize rows [b*8, b*8+8) -> fp8 pre-swizzled ========
  {
    const int row = b * 8 + (t >> 5);
    const int l32 = t & 31;
    float4 v = ((const float4*)(X + (size_t)row * 128))[l32];
    float s = v.x * v.x + v.y * v.y + v.z * v.z + v.w * v.w;
    s += __shfl_xor(s, 1);
    s += __shfl_xor(s, 2);
    s += __shfl_xor(s, 4);
    s += __shfl_xor(s, 8);
    s += __shfl_xor(s, 16);
    const float inv = scaleAB * rsqrtf(fmaxf(s, 1e-24f));
    int pk = __builtin_amdgcn_cvt_pk_fp8_f32(v.x * inv, v.y * inv, 0, false);
    pk = __builtin_amdgcn_cvt_pk_fp8_f32(v.z * inv, v.w * inv, pk, true);
    const int chunk = l32 >> 2;
    const int off = ((chunk ^ (row & 7)) << 4) + ((l32 & 3) << 2);
    *(unsigned int*)(Y8 + (size_t)row * 128 + off) = (unsigned)pk;
  }
  grid_bar(&bar[0], &bar[1], nb);  // Y8 visible grid-wide

  // ==== phase 1: similarity pass (R24 body; s is already *log2e) ========
  {
    const int bi = b >> 4, c = b & 15;  // 64 row-panels x 16 col-chunks
    const int i0 = bi * 128;
    const int j0 = c * 512;  // cols [j0, j0+512)

#pragma unroll
    for (int k = 0; k < 4; ++k) {
      const int c0 = w * 64 + k * 256;  // wave-uniform 16B-chunk index
      const int cc = c0 + lane;
      __builtin_amdgcn_global_load_lds(
          (glb_u32*)(Y8 + (size_t)i0 * 128 + (size_t)cc * 16),
          (lds_u32*)((unsigned char*)&As[0][0] + c0 * 16), 16, 0, 0);
    }
#pragma unroll
    for (int k = 0; k < 2; ++k) {
      const int c0 = w * 64 + k * 256;
      const int cc = c0 + lane;
      __builtin_amdgcn_global_load_lds(
          (glb_u32*)(Y8 + (size_t)j0 * 128 + (size_t)cc * 16),
          (lds_u32*)((unsigned char*)&Bs[0][0][0] + c0 * 16), 16, 0, 0);
    }
    if (t < 128) labR[t] = lab[i0 + t];
    __syncthreads();  // drains vmcnt (global_load_lds) + lgkmcnt

    const int quad = lane >> 4, l16 = lane & 15;
    const int rbase = w * 32;  // wave owns rows [rbase, rbase+32)
    const int sw = l16 & 7;

    int lr[2][4];
#pragma unroll
    for (int pi = 0; pi < 2; ++pi)
#pragma unroll
      for (int r = 0; r < 4; ++r)
        lr[pi][r] = labR[rbase + pi * 16 + quad * 4 + r];

    float trow[2][4] = {};  // row exp-sums (diag excluded)
    float pr[2][4] = {};    // row positive exp-sums
    float sacc = 0.f;       // sum of s*log2e over positives (non-self)

    for (int jt = 0; jt < 8; ++jt) {
      const int cur = jt & 1;
      const int jt0 = j0 + jt * 64;

      if (jt < 7) {  // prefetch next half-tile into the other buffer
        const unsigned char* src = Y8 + (size_t)(jt0 + 64) * 128;
        unsigned char* dst = (unsigned char*)&Bs[cur ^ 1][0][0];
#pragma unroll
        for (int k = 0; k < 2; ++k) {
          const int c0 = w * 64 + k * 256;
          const int cc = c0 + lane;
          __builtin_amdgcn_global_load_lds((glb_u32*)(src + (size_t)cc * 16),
                                           (lds_u32*)(dst + c0 * 16), 16, 0,
                                           0);
        }
      }

      int lc[4], cg_[4];
#pragma unroll
      for (int pj = 0; pj < 4; ++pj) {
        cg_[pj] = jt0 + pj * 16 + l16;
        lc[pj] = lab[cg_[pj]];
      }

      f32x4 acc[2][4] = {};
#pragma unroll
      for (int ks = 0; ks < 4; ++ks) {
        const int ch = ks * 2 + (quad >> 1);
        const int off = ((ch ^ sw) << 4) + ((quad & 1) << 3);
        long af[2], bf[4];
#pragma unroll
        for (int p = 0; p < 2; ++p)
          af[p] = *(const long*)&As[rbase + p * 16 + l16][off];
#pragma unroll
        for (int p = 0; p < 4; ++p)
          bf[p] = *(const long*)&Bs[cur][p * 16 + l16][off];
#pragma unroll
        for (int pi = 0; pi < 2; ++pi)
#pragma unroll
          for (int pj = 0; pj < 4; ++pj)
            acc[pi][pj] = __builtin_amdgcn_mfma_f32_16x16x32_fp8_fp8(
                af[pi], bf[pj], acc[pi][pj], 0, 0, 0);
      }

      // branch-free epilogue: register-only accumulation; e = exp2(s2)
      const bool dphase = ((jt0 >> 7) == bi);  // wave-uniform
      if (dphase) {
#pragma unroll
        for (int pi = 0; pi < 2; ++pi)
#pragma unroll
          for (int pj = 0; pj < 4; ++pj)
#pragma unroll
            for (int r = 0; r < 4; ++r) {
              const float s2 = acc[pi][pj][r];
              const float e = exp2f(s2);
              const int rowl = rbase + pi * 16 + quad * 4 + r;
              const bool self = (i0 + rowl) == cg_[pj];
              const bool match = (lr[pi][r] == lc[pj]) && !self;
              trow[pi][r] += self ? 0.f : e;
              pr[pi][r] += match ? e : 0.f;
              sacc += match ? s2 : 0.f;
            }
      } else {
#pragma unroll
        for (int pi = 0; pi < 2; ++pi)
#pragma unroll
          for (int pj = 0; pj < 4; ++pj)
#pragma unroll
            for (int r = 0; r < 4; ++r) {
              const float s2 = acc[pi][pj][r];
              const float e = exp2f(s2);
              const bool match = (lr[pi][r] == lc[pj]);
              trow[pi][r] += e;
              pr[pi][r] += match ? e : 0.f;
              sacc += match ? s2 : 0.f;
            }
      }
      __syncthreads();  // buffer handoff + drains next-phase staging
    }

    // flush: reduce across the 16 col-lanes, write-once partials
#pragma unroll
    for (int pi = 0; pi < 2; ++pi)
#pragma unroll
      for (int r = 0; r < 4; ++r) {
        float v = trow[pi][r], q = pr[pi][r];
        v += __shfl_xor(v, 1);
        q += __shfl_xor(q, 1);
        v += __shfl_xor(v, 2);
        q += __shfl_xor(q, 2);
        v += __shfl_xor(v, 4);
        q += __shfl_xor(q, 4);
        v += __shfl_xor(v, 8);
        q += __shfl_xor(q, 8);
        if (l16 == 0) {
          const int row = rbase + pi * 16 + quad * 4 + r;
          P[c * N + i0 + row] = v;  // (u + p) partial for this chunk
          Q[c * N + i0 + row] = q;  // p partial
        }
      }
#pragma unroll
    for (int m = 1; m < 64; m <<= 1) sacc += __shfl_xor(sacc, m);
    if (lane == 0) sS[w] = sacc;
    __syncthreads();
    if (t == 0)
      S[b] = (sS[0] + sS[1] + sS[2] + sS[3]) * 0.69314718056f;  // * ln2
  }
  grid_bar(&bar[2], &bar[3], nb);  // P/Q/S visible grid-wide

  // ==== phase 2: finalize on blocks 0..31 (256 rows each) ===============
  if (b < 32) {
    hist[t] = 0;
    __syncthreads();
    for (int i = t; i < N; i += 256) atomicAdd(&hist[lab[i] & 255], 1);
    __syncthreads();

    const int i = b * 256 + t;
    float tot = 0.f, p = 0.f;
#pragma unroll
    for (int cc = 0; cc < 16; ++cc) {
      tot += P[cc * N + i];
      p += Q[cc * N + i];
    }
    const float u = tot - p;
    const float cnti = (float)(hist[lab[i] & 255] - 1);
    float local = cnti * __logf(u) + p / u;
    if (t < 32) local -= S[b * 32 + t];  // fold this block's S-slice
#pragma unroll
    for (int m = 1; m < 64; m <<= 1) local += __shfl_xor(local, m);
    if (lane == 0) red[w] = local;
    __syncthreads();
    if (t == 0) {
      float np = 0.f;
      for (int k = 0; k < 256; ++k) {
        const float m = (float)hist[k];
        np += m * m;
      }
      atomicAdd(out, (red[0] + red[1] + red[2] + red[3]) / (np - (float)N));
    }
  }
}

// ---------------------------------------------------------------------------
extern "C" void kernel_launch(void* const* d_in, const int* in_sizes, int n_in,
                              void* d_out, int out_size, void* d_ws,
                              size_t ws_size, hipStream_t stream) {
  const float* X = (const float*)d_in[0];
  const int* lab = (const int*)d_in[1];
  float* out = (float*)d_out;

  const int N = in_sizes[1];  // 8192; D fixed at 128

  // workspace: Y8 (1MB) | P[16][N] (512KB) | Q[16][N] (512KB) | S[1024] | bar
  unsigned char* Y8 = (unsigned char*)d_ws;
  float* P = (float*)(Y8 + (size_t)N * 128);
  float* Q = P + 16 * (size_t)N;
  float* S = Q + 16 * (size_t)N;
  int* bar = (int*)(S + 1024);

  // sqrt(log2e / T): MFMA then outputs s*log2e so the epilogue is raw exp2
  const float scaleAB = 2.68579102f;  // sqrt(1.44269504 / 0.2)

  init_kernel<<<1, 64, 0, stream>>>(bar, out);
  const int nblk = (N / 128) * 16;  // 1024 = 256 CU x 4 blocks/CU (exact)
  fused_kernel<<<nblk, 256, 0, stream>>>(X, lab, Y8, P, Q, S, bar, out,
                                         scaleAB, N);
}

// Round 7
// 138.680 us; speedup vs baseline: 3.5418x; 3.5418x over previous
//
#include <hip/hip_runtime.h>
#include <math.h>

typedef float f32x4 __attribute__((ext_vector_type(4)));

// ---------------------------------------------------------------------------
// R27: pass1 with ZERO synchronization in the hot loop.
//
// Evidence: pass1 was ~40-45us across four structures (R0 triangular+global
// atomics, R23 512blk, R24 1024blk branch-free, R26 fused) while issue-cycle
// arithmetic says ~13us (67M exps = 6.8us trans + ~6us VALU). The invariant
// was the per-phase __syncthreads lockstep: 8x per block, every wave drains
// vmcnt(0) on the LDS staging loads with only 4 waves/SIMD to cover it
// (VALUBusy 24% = ~70% stall). Y8 is 1MB and fits in EVERY XCD's 4MB L2 --
// LDS staging of L2-resident data is pure overhead. R27 deletes it: A
// fragments live in registers (64B/thread, loaded once), B fragments are
// 8B global->register gathers (L2-hot, 16 independent loads per tile).
// No swizzle (it existed only for global_load_lds), no LDS tiles, no
// barriers: waves free-run, latencies overlap via TLP (>=16 waves/CU).
// B traffic rises 4x (each wave reads the tile) = 256MB from L2 at 34TB/s
// = 7us, hidden. R26's exp2 folding kept (validated absmax 0): rows are
// scaled by sqrt(log2e/T) so epilogue is raw exp2f; sacc *= ln2 at flush.
// ---------------------------------------------------------------------------

// Kernel 1: row normalization -> plain packed fp8 e4m3 rows. Zeroes out[0].
__global__ __launch_bounds__(256) void norm_kernel(
    const float* __restrict__ X, unsigned char* __restrict__ Y8,
    float* __restrict__ out, float scaleAB) {
  int t = threadIdx.x;
  int row = blockIdx.x * 8 + (t >> 5);
  int l32 = t & 31;
  float4 v = ((const float4*)(X + (size_t)row * 128))[l32];
  float s = v.x * v.x + v.y * v.y + v.z * v.z + v.w * v.w;
  s += __shfl_xor(s, 1);
  s += __shfl_xor(s, 2);
  s += __shfl_xor(s, 4);
  s += __shfl_xor(s, 8);
  s += __shfl_xor(s, 16);
  float inv = scaleAB * rsqrtf(fmaxf(s, 1e-24f));
  int pk = __builtin_amdgcn_cvt_pk_fp8_f32(v.x * inv, v.y * inv, 0, false);
  pk = __builtin_amdgcn_cvt_pk_fp8_f32(v.z * inv, v.w * inv, pk, true);
  *(unsigned int*)(Y8 + (size_t)row * 128 + l32 * 4) = (unsigned)pk;
  if (blockIdx.x == 0 && t == 0) out[0] = 0.f;
}

// ---------------------------------------------------------------------------
// Kernel 2: similarity pass, register-streaming. 64 panels x 16 chunks =
// 1024 blocks x 256 thr. Wave w owns rows [w*32, w*32+32) of its panel;
// loops over 8 64-col B tiles with direct global gathers. Only LDS: sS[4]
// for the block-scalar reduce (one trailing barrier, outside the hot loop).
__global__ __launch_bounds__(256, 4) void pass1_kernel(
    const unsigned char* __restrict__ Y8, const int* __restrict__ lab,
    float* __restrict__ P, float* __restrict__ Q, float* __restrict__ S,
    int N) {
  __shared__ float sS[4];

  const int b = blockIdx.x;
  const int bi = b >> 4, c = b & 15;  // 64 row-panels x 16 col-chunks
  const int i0 = bi * 128;
  const int j0 = c * 512;  // cols [j0, j0+512)
  const int t = threadIdx.x;
  const int w = t >> 6, lane = t & 63;
  const int quad = lane >> 4, l16 = lane & 15;
  const int rbase = w * 32;     // wave owns rows [rbase, rbase+32)
  const int colb = quad * 8;    // byte offset of this lane's 8B in a 32B k-chunk

  // ---- A fragments: loaded once, register-resident for all 8 tiles ----
  long af[4][2];
#pragma unroll
  for (int ks = 0; ks < 4; ++ks)
#pragma unroll
    for (int p = 0; p < 2; ++p)
      af[ks][p] = *(const long*)(Y8 +
                                 (size_t)(i0 + rbase + p * 16 + l16) * 128 +
                                 ks * 32 + colb);

  int lr[2][4];
#pragma unroll
  for (int pi = 0; pi < 2; ++pi)
#pragma unroll
    for (int r = 0; r < 4; ++r)
      lr[pi][r] = lab[i0 + rbase + pi * 16 + quad * 4 + r];

  float trow[2][4] = {};  // row exp-sums (diag excluded)
  float pr[2][4] = {};    // row positive exp-sums
  float sacc = 0.f;       // sum of s*log2e over positives (non-self)

#pragma unroll 2
  for (int jt = 0; jt < 8; ++jt) {
    const int jt0 = j0 + jt * 64;

    int lc[4];
#pragma unroll
    for (int pj = 0; pj < 4; ++pj) lc[pj] = lab[jt0 + pj * 16 + l16];

    f32x4 acc[2][4] = {};
#pragma unroll
    for (int ks = 0; ks < 4; ++ks) {
      long bf[4];
#pragma unroll
      for (int p = 0; p < 4; ++p)
        bf[p] = *(const long*)(Y8 +
                               (size_t)(jt0 + p * 16 + l16) * 128 +
                               ks * 32 + colb);
#pragma unroll
      for (int pi = 0; pi < 2; ++pi)
#pragma unroll
        for (int pj = 0; pj < 4; ++pj)
          acc[pi][pj] = __builtin_amdgcn_mfma_f32_16x16x32_fp8_fp8(
              af[ks][pi], bf[pj], acc[pi][pj], 0, 0, 0);
    }

    // branch-free epilogue: register-only accumulation; e = exp2(s*log2e)
    const bool dphase = ((jt0 >> 7) == bi);  // wave-uniform
    if (dphase) {
#pragma unroll
      for (int pi = 0; pi < 2; ++pi)
#pragma unroll
        for (int pj = 0; pj < 4; ++pj)
#pragma unroll
          for (int r = 0; r < 4; ++r) {
            const float s2 = acc[pi][pj][r];
            const float e = exp2f(s2);
            const int rowl = rbase + pi * 16 + quad * 4 + r;
            const bool self = (i0 + rowl) == (jt0 + pj * 16 + l16);
            const bool match = (lr[pi][r] == lc[pj]) && !self;
            trow[pi][r] += self ? 0.f : e;
            pr[pi][r] += match ? e : 0.f;
            sacc += match ? s2 : 0.f;
          }
    } else {
#pragma unroll
      for (int pi = 0; pi < 2; ++pi)
#pragma unroll
        for (int pj = 0; pj < 4; ++pj)
#pragma unroll
          for (int r = 0; r < 4; ++r) {
            const float s2 = acc[pi][pj][r];
            const float e = exp2f(s2);
            const bool match = (lr[pi][r] == lc[pj]);
            trow[pi][r] += e;
            pr[pi][r] += match ? e : 0.f;
            sacc += match ? s2 : 0.f;
          }
    }
  }

  // ---- flush: reduce across the 16 col-lanes, write-once partials ----
#pragma unroll
  for (int pi = 0; pi < 2; ++pi)
#pragma unroll
    for (int r = 0; r < 4; ++r) {
      float v = trow[pi][r], q = pr[pi][r];
      v += __shfl_xor(v, 1);
      q += __shfl_xor(q, 1);
      v += __shfl_xor(v, 2);
      q += __shfl_xor(q, 2);
      v += __shfl_xor(v, 4);
      q += __shfl_xor(q, 4);
      v += __shfl_xor(v, 8);
      q += __shfl_xor(q, 8);
      if (l16 == 0) {
        const int row = rbase + pi * 16 + quad * 4 + r;
        P[c * N + i0 + row] = v;  // (u + p) partial for this chunk
        Q[c * N + i0 + row] = q;  // p partial
      }
    }
#pragma unroll
  for (int m = 1; m < 64; m <<= 1) sacc += __shfl_xor(sacc, m);
  if (lane == 0) sS[w] = sacc;
  __syncthreads();  // only barrier in the kernel (outside hot loop)
  if (t == 0)
    S[b] = (sS[0] + sS[1] + sS[2] + sS[3]) * 0.69314718056f;  // * ln2
}

// ---------------------------------------------------------------------------
// Kernel 3: parallel finalize — 32 blocks x 256 thr, 256 rows each.
// Each block builds the label histogram in LDS, folds the 16 chunk-partials
// per row, subtracts its S-slice, adds blk/(np-N) into out[0] (one device
// atomic per block; out zeroed by norm upstream in the stream).
__global__ __launch_bounds__(256) void finalize_kernel(
    const int* __restrict__ lab, const float* __restrict__ P,
    const float* __restrict__ Q, const float* __restrict__ S,
    float* __restrict__ out, int N) {
  __shared__ int hist[256];
  __shared__ float red[4];
  const int b = blockIdx.x, t = threadIdx.x;
  const int lane = t & 63, w = t >> 6;
  hist[t] = 0;
  __syncthreads();
  for (int i = t; i < N; i += 256) atomicAdd(&hist[lab[i] & 255], 1);
  __syncthreads();

  const int i = b * 256 + t;
  float tot = 0.f, p = 0.f;
#pragma unroll
  for (int cc = 0; cc < 16; ++cc) {
    tot += P[cc * N + i];
    p += Q[cc * N + i];
  }
  const float u = tot - p;
  const float cnti = (float)(hist[lab[i] & 255] - 1);
  float local = cnti * __logf(u) + p / u;
  if (t < 32) local -= S[b * 32 + t];  // fold this block's S-slice
#pragma unroll
  for (int m = 1; m < 64; m <<= 1) local += __shfl_xor(local, m);
  if (lane == 0) red[w] = local;
  __syncthreads();
  if (t == 0) {
    float np = 0.f;
    for (int k = 0; k < 256; ++k) {
      const float m = (float)hist[k];
      np += m * m;
    }
    atomicAdd(out, (red[0] + red[1] + red[2] + red[3]) / (np - (float)N));
  }
}

// ---------------------------------------------------------------------------
extern "C" void kernel_launch(void* const* d_in, const int* in_sizes, int n_in,
                              void* d_out, int out_size, void* d_ws,
                              size_t ws_size, hipStream_t stream) {
  const float* X = (const float*)d_in[0];
  const int* lab = (const int*)d_in[1];
  float* out = (float*)d_out;

  const int N = in_sizes[1];  // 8192; D fixed at 128

  // workspace: Y8 (1MB) | P[16][N] (512KB) | Q[16][N] (512KB) | S[1024]
  unsigned char* Y8 = (unsigned char*)d_ws;
  float* P = (float*)(Y8 + (size_t)N * 128);
  float* Q = P + 16 * (size_t)N;
  float* S = Q + 16 * (size_t)N;

  // sqrt(log2e / T): MFMA outputs s*log2e so the epilogue is raw exp2
  const float scaleAB = 2.68579102f;  // sqrt(1.44269504 / 0.2)

  norm_kernel<<<N / 8, 256, 0, stream>>>(X, Y8, out, scaleAB);

  const int nblk = (N / 128) * 16;  // 64 panels x 16 chunks = 1024
  pass1_kernel<<<nblk, 256, 0, stream>>>(Y8, lab, P, Q, S, N);
  finalize_kernel<<<32, 256, 0, stream>>>(lab, P, Q, S, out, N);
}

// Round 9
// 100.356 us; speedup vs baseline: 4.8943x; 1.3819x over previous
//
#include <hip/hip_runtime.h>
#include <math.h>

typedef float f32x4 __attribute__((ext_vector_type(4)));
typedef __attribute__((address_space(3))) unsigned int lds_u32;
typedef __attribute__((address_space(1))) const unsigned int glb_u32;

// ---------------------------------------------------------------------------
// R28/R29 (identical resubmit; R28's bench was an infra double-failure, audit
// found no fault mode -- same as R3->R4 which cleared on resubmission).
//
// Occupancy-first pass1. R27 post-mortem: no-LDS register streaming SPILLED
// (WRITE_SIZE 16.4MB = ~60B/thread scratch) and scattered 8B B-gathers (16
// lines/instr) are slower than LDS staging -> 77us. R26: software grid
// barrier = fence storm -> 444us. R24 (LDS + 1 barrier/phase) inferred at
// ~37us vs ~13us issue floor; weakness: 34.8KB LDS -> 4 blocks/CU -> 4
// waves/SIMD, no latency hiding.
//
// R28 keeps R24's proven staged/swizzled schedule but triples resident
// waves: 2048 blocks (128 panels of 64 rows x 16 chunks), 256 thr, LDS =
// Bs[2][64][128] = 16.4KB ONLY (A-fragments = 4 one-time swizzled global
// gathers into registers, amortized over 8 phases). ~65 VGPR at
// __launch_bounds__(256,6) (cap 85, no spill) -> 6 blocks/CU, 24 waves/CU,
// + 512 extra blocks to fill the tail. exp2 scale-folding kept (validated
// R26/R27): rows scaled by sqrt(log2e/T), epilogue raw exp2f, sacc *= ln2.
// ---------------------------------------------------------------------------

// Kernel 1: row normalization -> fp8 e4m3 rows PRE-SWIZZLED (16B chunk c of
// row r stored at chunk c ^ (r&7)); pass1 stages verbatim and applies the
// same XOR on reads (LDS bank-spread) and on its register A-gathers.
// Also zeroes out[0].
__global__ __launch_bounds__(256) void norm_kernel(
    const float* __restrict__ X, unsigned char* __restrict__ Y8,
    float* __restrict__ out, float scaleAB) {
  int t = threadIdx.x;
  int row = blockIdx.x * 8 + (t >> 5);
  int l32 = t & 31;
  float4 v = ((const float4*)(X + (size_t)row * 128))[l32];
  float s = v.x * v.x + v.y * v.y + v.z * v.z + v.w * v.w;
  s += __shfl_xor(s, 1);
  s += __shfl_xor(s, 2);
  s += __shfl_xor(s, 4);
  s += __shfl_xor(s, 8);
  s += __shfl_xor(s, 16);
  float inv = scaleAB * rsqrtf(fmaxf(s, 1e-24f));
  int pk = __builtin_amdgcn_cvt_pk_fp8_f32(v.x * inv, v.y * inv, 0, false);
  pk = __builtin_amdgcn_cvt_pk_fp8_f32(v.z * inv, v.w * inv, pk, true);
  int chunk = l32 >> 2;
  int off = ((chunk ^ (row & 7)) << 4) + ((l32 & 3) << 2);
  *(unsigned int*)(Y8 + (size_t)row * 128 + off) = (unsigned)pk;
  if (blockIdx.x == 0 && t == 0) out[0] = 0.f;
}

// ---------------------------------------------------------------------------
// Kernel 2: similarity pass. Block (bi,c): rows [bi*64, bi*64+64) x cols
// [c*512, c*512+512) in 8 phases of 64 cols, double-buffered LDS B tiles,
// one __syncthreads per phase (drains next-tile staging + read-done).
__global__ __launch_bounds__(256, 6) void pass1_kernel(
    const unsigned char* __restrict__ Y8, const int* __restrict__ lab,
    float* __restrict__ P, float* __restrict__ Q, float* __restrict__ S,
    int N) {
  __shared__ unsigned char Bs[2][64][128];  // chunk cc at (cc ^ (row&7))*16
  __shared__ float sS[4];

  const int b = blockIdx.x;
  const int bi = b >> 4, c = b & 15;  // 128 row-panels x 16 col-chunks
  const int i0 = bi * 64;
  const int j0 = c * 512;  // cols [j0, j0+512)
  const int t = threadIdx.x;
  const int w = t >> 6, lane = t & 63;
  const int quad = lane >> 4, l16 = lane & 15;
  const int rbase = w * 16;  // wave owns rows [rbase, rbase+16)
  const int sw = l16 & 7;

  // ---- stage first B tile (8KB, 2 x 1KB segments per wave) ----
#pragma unroll
  for (int k = 0; k < 2; ++k) {
    const int c0 = w * 64 + k * 256;  // wave-uniform 16B-chunk index
    const int cc = c0 + lane;
    __builtin_amdgcn_global_load_lds(
        (glb_u32*)(Y8 + (size_t)j0 * 128 + (size_t)cc * 16),
        (lds_u32*)((unsigned char*)&Bs[0][0][0] + c0 * 16), 16, 0, 0);
  }

  // ---- A fragments: ONE-TIME swizzled global gathers -> registers ----
  // (L2-hot; amortized over all 8 phases -- unlike R27's per-tile gathers)
  long af[4];
  {
    const size_t abase = (size_t)(i0 + rbase + l16) * 128;
#pragma unroll
    for (int ks = 0; ks < 4; ++ks) {
      const int ch = ks * 2 + (quad >> 1);
      const int off = ((ch ^ sw) << 4) + ((quad & 1) << 3);
      af[ks] = *(const long*)(Y8 + abase + off);
    }
  }
  int lr[4];
#pragma unroll
  for (int r = 0; r < 4; ++r) lr[r] = lab[i0 + rbase + quad * 4 + r];

  float trow[4] = {};  // row exp-sums (diag excluded)
  float pr[4] = {};    // row positive exp-sums
  float sacc = 0.f;    // sum of s*log2e over positives (non-self)

  __syncthreads();  // first B tile staged (vmcnt drained)

  for (int jt = 0; jt < 8; ++jt) {
    const int cur = jt & 1;
    const int jt0 = j0 + jt * 64;

    if (jt < 7) {  // prefetch next tile into the other buffer
      const unsigned char* src = Y8 + (size_t)(jt0 + 64) * 128;
      unsigned char* dst = (unsigned char*)&Bs[cur ^ 1][0][0];
#pragma unroll
      for (int k = 0; k < 2; ++k) {
        const int c0 = w * 64 + k * 256;
        const int cc = c0 + lane;
        __builtin_amdgcn_global_load_lds((glb_u32*)(src + (size_t)cc * 16),
                                         (lds_u32*)(dst + c0 * 16), 16, 0, 0);
      }
    }

    int lc[4];
#pragma unroll
    for (int pj = 0; pj < 4; ++pj) lc[pj] = lab[jt0 + pj * 16 + l16];

    f32x4 acc[4] = {};
#pragma unroll
    for (int ks = 0; ks < 4; ++ks) {
      const int ch = ks * 2 + (quad >> 1);
      const int off = ((ch ^ sw) << 4) + ((quad & 1) << 3);
      long bf[4];
#pragma unroll
      for (int p = 0; p < 4; ++p)
        bf[p] = *(const long*)&Bs[cur][p * 16 + l16][off];
#pragma unroll
      for (int pj = 0; pj < 4; ++pj)
        acc[pj] = __builtin_amdgcn_mfma_f32_16x16x32_fp8_fp8(af[ks], bf[pj],
                                                             acc[pj], 0, 0, 0);
    }

    // branch-free epilogue; e = exp2(s*log2e). Diagonal 64x64 tile iff
    // jt0 == i0 (both 64-aligned): self ⇔ local row == local col.
    if (jt0 == i0) {
#pragma unroll
      for (int pj = 0; pj < 4; ++pj)
#pragma unroll
        for (int r = 0; r < 4; ++r) {
          const float s2 = acc[pj][r];
          const float e = exp2f(s2);
          const int rowl = rbase + quad * 4 + r;
          const bool self = rowl == (pj * 16 + l16);
          const bool match = (lr[r] == lc[pj]) && !self;
          trow[r] += self ? 0.f : e;
          pr[r] += match ? e : 0.f;
          sacc += match ? s2 : 0.f;
        }
    } else {
#pragma unroll
      for (int pj = 0; pj < 4; ++pj)
#pragma unroll
        for (int r = 0; r < 4; ++r) {
          const float s2 = acc[pj][r];
          const float e = exp2f(s2);
          const bool match = (lr[r] == lc[pj]);
          trow[r] += e;
          pr[r] += match ? e : 0.f;
          sacc += match ? s2 : 0.f;
        }
    }
    __syncthreads();  // buffer handoff + drains next-phase staging
  }

  // ---- flush: reduce across the 16 col-lanes, write-once partials ----
#pragma unroll
  for (int r = 0; r < 4; ++r) {
    float v = trow[r], q = pr[r];
    v += __shfl_xor(v, 1);
    q += __shfl_xor(q, 1);
    v += __shfl_xor(v, 2);
    q += __shfl_xor(q, 2);
    v += __shfl_xor(v, 4);
    q += __shfl_xor(q, 4);
    v += __shfl_xor(v, 8);
    q += __shfl_xor(q, 8);
    if (l16 == 0) {
      const int row = rbase + quad * 4 + r;
      P[c * N + i0 + row] = v;  // (u + p) partial for this chunk
      Q[c * N + i0 + row] = q;  // p partial
    }
  }
#pragma unroll
  for (int m = 1; m < 64; m <<= 1) sacc += __shfl_xor(sacc, m);
  if (lane == 0) sS[w] = sacc;
  __syncthreads();
  if (t == 0)
    S[b] = (sS[0] + sS[1] + sS[2] + sS[3]) * 0.69314718056f;  // * ln2
}

// ---------------------------------------------------------------------------
// Kernel 3: parallel finalize — 32 blocks x 256 thr, 256 rows each.
// LDS label histogram, fold 16 chunk-partials per row, subtract this
// block's S-slice (64 of 2048), one device atomic per block into out[0].
__global__ __launch_bounds__(256) void finalize_kernel(
    const int* __restrict__ lab, const float* __restrict__ P,
    const float* __restrict__ Q, const float* __restrict__ S,
    float* __restrict__ out, int N) {
  __shared__ int hist[256];
  __shared__ float red[4];
  const int b = blockIdx.x, t = threadIdx.x;
  const int lane = t & 63, w = t >> 6;
  hist[t] = 0;
  __syncthreads();
  for (int i = t; i < N; i += 256) atomicAdd(&hist[lab[i] & 255], 1);
  __syncthreads();

  const int i = b * 256 + t;
  float tot = 0.f, p = 0.f;
#pragma unroll
  for (int cc = 0; cc < 16; ++cc) {
    tot += P[cc * N + i];
    p += Q[cc * N + i];
  }
  const float u = tot - p;
  const float cnti = (float)(hist[lab[i] & 255] - 1);
  float local = cnti * __logf(u) + p / u;
  if (t < 64) local -= S[b * 64 + t];  // fold this block's S-slice
#pragma unroll
  for (int m = 1; m < 64; m <<= 1) local += __shfl_xor(local, m);
  if (lane == 0) red[w] = local;
  __syncthreads();
  if (t == 0) {
    float np = 0.f;
    for (int k = 0; k < 256; ++k) {
      const float m = (float)hist[k];
      np += m * m;
    }
    atomicAdd(out, (red[0] + red[1] + red[2] + red[3]) / (np - (float)N));
  }
}

// ---------------------------------------------------------------------------
extern "C" void kernel_launch(void* const* d_in, const int* in_sizes, int n_in,
                              void* d_out, int out_size, void* d_ws,
                              size_t ws_size, hipStream_t stream) {
  const float* X = (const float*)d_in[0];
  const int* lab = (const int*)d_in[1];
  float* out = (float*)d_out;

  const int N = in_sizes[1];  // 8192; D fixed at 128

  // workspace: Y8 (1MB) | P[16][N] (512KB) | Q[16][N] (512KB) | S[2048]
  unsigned char* Y8 = (unsigned char*)d_ws;
  float* P = (float*)(Y8 + (size_t)N * 128);
  float* Q = P + 16 * (size_t)N;
  float* S = Q + 16 * (size_t)N;

  // sqrt(log2e / T): MFMA outputs s*log2e so the epilogue is raw exp2
  const float scaleAB = 2.68579102f;  // sqrt(1.44269504 / 0.2)

  norm_kernel<<<N / 8, 256, 0, stream>>>(X, Y8, out, scaleAB);

  const int nblk = (N / 64) * 16;  // 128 panels x 16 chunks = 2048
  pass1_kernel<<<nblk, 256, 0, stream>>>(Y8, lab, P, Q, S, N);
  finalize_kernel<<<32, 256, 0, stream>>>(lab, P, Q, S, out, N);
}